// Round 10
// baseline (692.924 us; speedup 1.0000x reference)
//
#include <hip/hip_runtime.h>
#include <hip/hip_bf16.h>
#include <math.h>

// Problem constants
#define NB   1024   // batch
#define NT   60     // time steps
#define NC   10     // in channels
#define NDM  256    // d_model
#define NH   16     // heads
#define NDH  16     // per-head value dim
#define NA   13     // num attention queries
#define NM   208    // NA*NH
#define NMO  128    // MLP out

// weff4 row: 128 groups x 32 floats; group g covers d=2g (slots 0..12) and
// d=2g+1 (slots 16..28); slots 13-15/29-31 are pad (never read).
#define WROW4 4096

// Workspace layout (floats)
#define OFF_WEFF  0
#define N_WEFF    (NH*14*WROW4)                // 917,504
#define OFF_BEFF  (OFF_WEFF + N_WEFF)
#define N_BEFF    (NM*NH*NA)                   // 43,264
#define OFF_VGT   (OFF_BEFF + N_BEFF)
#define N_VGT     (NB*NDM*64)                  // 16,777,216 (v transposed [b][d][64])
#define OFF_ATT   (OFF_VGT + N_VGT)
#define N_ATT     (NM*NB*NDH)                  // 3,407,872

#define LDS_FENCE() __asm__ __volatile__("s_waitcnt lgkmcnt(0)" ::: "memory")

// ---------------- K0: weff4[hk][mi][g][slot], m = 13*hk+mi
__global__ void ltae_weff(const float* __restrict__ Q, const float* __restrict__ Wk,
                          const float* __restrict__ bk, float* __restrict__ weff4,
                          float* __restrict__ beff2) {
    int blk = blockIdx.x;            // hk*14 + mi
    int hk = blk / 14, mi = blk - hk*14;
    int m  = hk*13 + mi;
    int mc = m > 207 ? 207 : m;      // slot (15,13) provably never read
    int d = threadIdx.x;
    float q0 = Q[mc*4+0], q1 = Q[mc*4+1], q2 = Q[mc*4+2], q3 = Q[mc*4+3];
    size_t base = (size_t)blk*WROW4 + (size_t)(d >> 1)*32 + (d & 1)*16;
#pragma unroll
    for (int ak = 0; ak < NA; ++ak) {
        int e = (ak*16 + hk)*4;
        float w = q0*Wk[(size_t)(e+0)*NDM + d] + q1*Wk[(size_t)(e+1)*NDM + d]
                + q2*Wk[(size_t)(e+2)*NDM + d] + q3*Wk[(size_t)(e+3)*NDM + d];
        weff4[base + ak] = w;
    }
    weff4[base+13] = 0.f; weff4[base+14] = 0.f; weff4[base+15] = 0.f;
    if (d < NA && m <= 207) {
        int e = (d*16 + hk)*4;
        beff2[(m*16 + hk)*NA + d] = q0*bk[e] + q1*bk[e+1] + q2*bk[e+2] + q3*bk[e+3];
    }
}

// ---------------- K1: conv 1x1 + GroupNorm -> vgT[b][d][64] (t-padded, coalesced)
#define VT_S 66
#define K1_LDS_BYTES ((NDM*VT_S + NT*NC)*4)

__launch_bounds__(1024, 8)
__global__ void ltae_convgn(const float* __restrict__ x, const float* __restrict__ Wc,
                            const float* __restrict__ bc, const float* __restrict__ gnw,
                            const float* __restrict__ gnb, float* __restrict__ vgT) {
    extern __shared__ float smem[];
    float* Vt = smem;
    float* xs = smem + NDM*VT_S;
    int b = blockIdx.x, tid = threadIdx.x;
    if (tid < NT*NC) xs[tid] = x[(size_t)b*NT*NC + tid];
    __syncthreads();
    {
        int d = tid >> 2, q = tid & 3;   // wave = 16 d = one GN group
        float wc[NC];
#pragma unroll
        for (int c = 0; c < NC; ++c) wc[c] = Wc[d*NC + c];
        float bcv = bc[d];
        float h[15];
        float s1 = 0.f, s2 = 0.f;
#pragma unroll
        for (int k = 0; k < 15; ++k) {
            int t = 15*q + k;
            float a = bcv;
#pragma unroll
            for (int c = 0; c < NC; ++c) a = fmaf(xs[t*NC + c], wc[c], a);
            h[k] = a; s1 += a; s2 += a*a;
        }
#pragma unroll
        for (int off = 1; off < 64; off <<= 1) {
            s1 += __shfl_xor(s1, off);
            s2 += __shfl_xor(s2, off);
        }
        float mean = s1 * (1.f/960.f);
        float var  = s2 * (1.f/960.f) - mean*mean;
        float rstd = rsqrtf(var + 1e-5f);
        float g = gnw[d], bb = gnb[d];
#pragma unroll
        for (int k = 0; k < 15; ++k)
            Vt[d*VT_S + 15*q + k] = (h[k]-mean)*rstd*g + bb;
    }
    __syncthreads();
    float* vb = vgT + (size_t)b*NDM*64;
    for (int i = tid; i < NDM*64; i += 1024) {
        int d = i >> 6, t = i & 63;
        vb[i] = (t < NT) ? Vt[d*VT_S + t] : 0.f;
    }
}

// ---------------- K2: scrambled attention; block = (b, hk-quadrant), wave = hk
// Both streams VMEM (in-order vmcnt): weights per-lane broadcast loads,
// v per-lane loads; manual 2x-unrolled double-buffer, no LDS in GEMM.
#define ACC_D(V, W0, W1, W2, W3) do { \
    acc[0]  = fmaf(V, W0.x, acc[0]);  acc[1]  = fmaf(V, W0.y, acc[1]); \
    acc[2]  = fmaf(V, W0.z, acc[2]);  acc[3]  = fmaf(V, W0.w, acc[3]); \
    acc[4]  = fmaf(V, W1.x, acc[4]);  acc[5]  = fmaf(V, W1.y, acc[5]); \
    acc[6]  = fmaf(V, W1.z, acc[6]);  acc[7]  = fmaf(V, W1.w, acc[7]); \
    acc[8]  = fmaf(V, W2.x, acc[8]);  acc[9]  = fmaf(V, W2.y, acc[9]); \
    acc[10] = fmaf(V, W2.z, acc[10]); acc[11] = fmaf(V, W2.w, acc[11]); \
    acc[12] = fmaf(V, W3.x, acc[12]); } while (0)

__launch_bounds__(256, 5)
__global__ void ltae_attn(const float* __restrict__ vgT, const float* __restrict__ weff4,
                          const float* __restrict__ beff2, float* __restrict__ attout) {
    __shared__ float wbuf[4*192];
    int bq = blockIdx.x;
    int b = bq >> 2, q = bq & 3;
    int tid = threadIdx.x;
    int wid = tid >> 6, lane = tid & 63;
    int hk = q*4 + wid;                              // tid-dependent -> stays on VMEM path
    int tk = lane;
    int mi    = (13*b) >> 10;                        // block-uniform
    int rstar = ((mi+1) << 10) - 13*b;               // switch iff <13
    int hb13  = (hk*1024 + b)*13;
    const float* __restrict__ vb = vgT + (size_t)b*NDM*64;

    float acc[13];
#pragma unroll
    for (int j = 0; j < 13; ++j) acc[j] = 0.f;

    // ---- pass A: row (hk, mi); 128 groups (2 d each); 2x-unrolled dbuf
    {
        const float4* __restrict__ wp = (const float4*)(weff4 + (size_t)(hk*14 + mi)*WROW4);
        const float*  __restrict__ vp = vb + tk;
        float4 wa0 = wp[0], wa1 = wp[1], wa2 = wp[2], wa3 = wp[3];
        float4 wa4 = wp[4], wa5 = wp[5], wa6 = wp[6], wa7 = wp[7];
        float va0 = vp[0], va1 = vp[64];
#pragma unroll 1
        for (int g = 0; g < 128; g += 2) {
            // prefetch group g+1
            float4 wb0 = wp[8],  wb1 = wp[9],  wb2 = wp[10], wb3 = wp[11];
            float4 wb4 = wp[12], wb5 = wp[13], wb6 = wp[14], wb7 = wp[15];
            float vb0 = vp[128], vb1 = vp[192];
            // compute group g
            ACC_D(va0, wa0, wa1, wa2, wa3);
            ACC_D(va1, wa4, wa5, wa6, wa7);
            // prefetch group g+2 (guarded)
            const float4* wp2 = (g < 126) ? wp + 16 : wp;
            const float*  vp2 = (g < 126) ? vp + 256 : vp;
            wa0 = wp2[0]; wa1 = wp2[1]; wa2 = wp2[2]; wa3 = wp2[3];
            wa4 = wp2[4]; wa5 = wp2[5]; wa6 = wp2[6]; wa7 = wp2[7];
            va0 = vp2[0]; va1 = vp2[64];
            // compute group g+1
            ACC_D(vb0, wb0, wb1, wb2, wb3);
            ACC_D(vb1, wb4, wb5, wb6, wb7);
            wp = wp2; vp = vp2;
        }
    }

    // ---- pass B (rare, block-uniform): row (hk, mi+1); single-buffered.
    if (rstar < 13) {
        int ustar = 60*rstar;
        int tstar = ustar / 13;
        float* wl = wbuf + wid*192;
        if (tk == tstar) {
#pragma unroll
            for (int j = 0; j < 13; ++j) wl[j] = acc[j];
        }
        LDS_FENCE();
        if (tk >= tstar) {
#pragma unroll
            for (int j = 0; j < 13; ++j) acc[j] = 0.f;
            const float4* __restrict__ wp = (const float4*)(weff4 + (size_t)(hk*14 + mi + 1)*WROW4);
            const float*  __restrict__ vp = vb + tk;
#pragma unroll 1
            for (int g = 0; g < 128; ++g) {
                float4 w0 = wp[0], w1 = wp[1], w2 = wp[2], w3 = wp[3];
                float4 w4 = wp[4], w5 = wp[5], w6 = wp[6], w7 = wp[7];
                float v0 = vp[0], v1 = vp[64];
                ACC_D(v0, w0, w1, w2, w3);
                ACC_D(v1, w4, w5, w6, w7);
                wp += 8; vp += 128;
            }
        }
        if (tk == tstar) {
#pragma unroll
            for (int j = 0; j < 13; ++j)
                if (13*tk + j < ustar) acc[j] = wl[j];
        }
    }

    // ---- phased softmax + AV (5 u-ranges over wave-private 192-float slot)
    float* myC = wbuf + wid*192;
    int dh = lane >> 2, cc = lane & 3;
    float vreg[15];
#pragma unroll
    for (int j = 0; j < 15; ++j) vreg[j] = vb[(hk*16 + dh)*64 + cc + 4*j];

    const int ULO[5] = {0, 180, 360, 540, 720};
    const int RLO[5] = {0, 3, 6, 9, 12};
    const int RHI[5] = {3, 6, 9, 12, 13};
#pragma unroll 1
    for (int p = 0; p < 5; ++p) {
        int ulo = ULO[p];
        int uhi = (p == 4) ? 780 : ulo + 180;
        if (tk < NT) {
#pragma unroll
            for (int j = 0; j < 13; ++j) {
                int u = 13*tk + j;
                if (u >= ulo && u < uhi) myC[u - ulo] = acc[j];
            }
        }
        LDS_FENCE();
        for (int r = RLO[p]; r < RHI[p]; ++r) {
            int n = hb13 + r;
            int m = n >> 10;                         // exact variant for this row
            int brow = (m*16 + hk)*13;
            float logit = -1e30f;
            if (lane < NT) {
                int u  = r*60 + lane;
                int ak = u % 13;
                logit = (myC[u - ulo] + beff2[brow + ak]) * 0.5f;
            }
            float mx = logit;
#pragma unroll
            for (int off = 32; off; off >>= 1) mx = fmaxf(mx, __shfl_xor(mx, off));
            float e = (lane < NT) ? __expf(logit - mx) : 0.f;
            float s = e;
#pragma unroll
            for (int off = 32; off; off >>= 1) s += __shfl_xor(s, off);
            float attn = e / s;
            if (lane < NT) myC[r*60 - ulo + lane] = attn;  // same-wave in-order LDS
            LDS_FENCE();
            float a = 0.f;
#pragma unroll
            for (int j = 0; j < 15; ++j)
                a = fmaf(myC[r*60 - ulo + cc + 4*j], vreg[j], a);
            a += __shfl_xor(a, 1);
            a += __shfl_xor(a, 2);
            if (cc == 0) attout[(size_t)n*NDH + dh] = a;
        }
    }
}

// ---------------- K3: MLP + BN(eval) + ReLU + GroupNorm(16,128); 16 rows/block,
// each thread computes 2 rows per W1-row load (halves W1 traffic).
__launch_bounds__(1024)
__global__ void ltae_mlp(const float* __restrict__ attout, const float* __restrict__ W1,
                         const float* __restrict__ b1, const float* __restrict__ bnw,
                         const float* __restrict__ bnb, const float* __restrict__ bnrm,
                         const float* __restrict__ bnrv, const float* __restrict__ gow,
                         const float* __restrict__ gob, float* __restrict__ out) {
    __shared__ float f[16][NDM];
    int tid = threadIdx.x;
    int sl  = tid >> 7;          // 0..7
    int j   = tid & 127;
    int base = blockIdx.x << 4;  // 16 sids per block; sid = a2*1024 + b2
    for (int k = tid; k < 16*NDM; k += 1024) {
        int s = k >> 8, c = k & 255;
        int sid2 = base + s;
        int aa = sid2 >> 10, bb = sid2 & 1023;
        int h2 = c >> 4, dhh = c & 15;
        f[s][c] = attout[((size_t)((aa*16 + h2)*1024 + bb))*NDH + dhh];
    }
    __syncthreads();
    const float* fr0 = f[sl];
    const float* fr1 = f[sl + 8];
    const float* w   = &W1[(size_t)j*NDM];
    float bj = b1[j];
    float acc0 = bj, acc1 = bj;
    for (int c = 0; c < NDM; c += 4) {
        float4 wv = *(const float4*)&w[c];
        acc0 += wv.x*fr0[c] + wv.y*fr0[c+1] + wv.z*fr0[c+2] + wv.w*fr0[c+3];
        acc1 += wv.x*fr1[c] + wv.y*fr1[c+1] + wv.z*fr1[c+2] + wv.w*fr1[c+3];
    }
    float rs = rsqrtf(bnrv[j] + 1e-5f);
    float sc = rs * bnw[j];
    float sh = bnb[j] - bnrm[j]*sc;
    float y0 = fmaxf(acc0*sc + sh, 0.f);
    float y1 = fmaxf(acc1*sc + sh, 0.f);
    float a1 = y0, b1s = y0*y0, a2 = y1, b2s = y1*y1;
#pragma unroll
    for (int off = 1; off < 8; off <<= 1) {
        a1  += __shfl_xor(a1, off);
        b1s += __shfl_xor(b1s, off);
        a2  += __shfl_xor(a2, off);
        b2s += __shfl_xor(b2s, off);
    }
    float gw = gow[j], gb = gob[j];
    {
        float mean = a1 * 0.125f;
        float var  = b1s * 0.125f - mean*mean;
        float o = (y0 - mean) * rsqrtf(var + 1e-5f) * gw + gb;
        int sid = base + sl, aa = sid >> 10, bb = sid & 1023;
        out[((size_t)bb*NA + aa)*NMO + j] = o;
    }
    {
        float mean = a2 * 0.125f;
        float var  = b2s * 0.125f - mean*mean;
        float o = (y1 - mean) * rsqrtf(var + 1e-5f) * gw + gb;
        int sid = base + sl + 8, aa = sid >> 10, bb = sid & 1023;
        out[((size_t)bb*NA + aa)*NMO + j] = o;
    }
}

extern "C" void kernel_launch(void* const* d_in, const int* in_sizes, int n_in,
                              void* d_out, int out_size, void* d_ws, size_t ws_size,
                              hipStream_t stream) {
    const float* x    = (const float*)d_in[0];
    const float* Wc   = (const float*)d_in[1];
    const float* bc   = (const float*)d_in[2];
    const float* gnw  = (const float*)d_in[3];
    const float* gnb  = (const float*)d_in[4];
    const float* Q    = (const float*)d_in[5];
    const float* Wk   = (const float*)d_in[6];
    const float* bk   = (const float*)d_in[7];
    const float* W1   = (const float*)d_in[8];
    const float* b1   = (const float*)d_in[9];
    const float* bnw  = (const float*)d_in[10];
    const float* bnb  = (const float*)d_in[11];
    const float* bnrm = (const float*)d_in[12];
    const float* bnrv = (const float*)d_in[13];
    const float* gow  = (const float*)d_in[14];
    const float* gob  = (const float*)d_in[15];

    float* ws     = (float*)d_ws;
    float* weff4  = ws + OFF_WEFF;
    float* beff2  = ws + OFF_BEFF;
    float* vgT    = ws + OFF_VGT;
    float* attout = ws + OFF_ATT;
    float* outp   = (float*)d_out;

    hipLaunchKernelGGL(ltae_weff, dim3(NH*14), dim3(256), 0, stream, Q, Wk, bk, weff4, beff2);
    hipFuncSetAttribute((const void*)ltae_convgn,
                        hipFuncAttributeMaxDynamicSharedMemorySize, K1_LDS_BYTES);
    hipLaunchKernelGGL(ltae_convgn, dim3(NB), dim3(1024), K1_LDS_BYTES, stream,
                       x, Wc, bc, gnw, gnb, vgT);
    hipLaunchKernelGGL(ltae_attn, dim3(NB*4), dim3(256), 0, stream,
                       vgT, weff4, beff2, attout);
    hipLaunchKernelGGL(ltae_mlp, dim3(NA*NB/16), dim3(1024), 0, stream,
                       attout, W1, b1, bnw, bnb, bnrm, bnrv, gow, gob, outp);
}

// Round 12
// 497.574 us; speedup vs baseline: 1.3926x; 1.3926x over previous
//
#include <hip/hip_runtime.h>
#include <hip/hip_bf16.h>
#include <math.h>

// Problem constants
#define NB   1024   // batch
#define NT   60     // time steps
#define NC   10     // in channels
#define NDM  256    // d_model
#define NH   16     // heads
#define NDH  16     // per-head value dim
#define NA   13     // num attention queries
#define NM   208    // NA*NH
#define NMO  128    // MLP out
#define WROW (NDM*NA)   // 3328 floats per weight row = 16 chunks x 208

// Workspace layout (floats)
#define OFF_WEFF  0
#define N_WEFF    (NH*14*WROW)                 // 745,472 (compact (hk,mi) rows)
#define OFF_BEFF  (OFF_WEFF + N_WEFF)
#define N_BEFF    (NM*NH*NA)                   // 43,264
#define OFF_VGT   (OFF_BEFF + N_BEFF)
#define N_VGT     (NB*NDM*64)                  // 16,777,216 (v transposed [b][d][64])
#define OFF_ATT   (OFF_VGT + N_VGT)
#define N_ATT     (NM*NB*NDH)                  // 3,407,872

#define LDS_FENCE() __asm__ __volatile__("s_waitcnt lgkmcnt(0)" ::: "memory")

// ---------------- K0: weff3[hk][mi][chunk c][ak][d16], m = 13*hk+mi
__global__ void ltae_weff(const float* __restrict__ Q, const float* __restrict__ Wk,
                          const float* __restrict__ bk, float* __restrict__ weff3,
                          float* __restrict__ beff2) {
    int blk = blockIdx.x;            // hk*14 + mi
    int hk = blk / 14, mi = blk - hk*14;
    int m  = hk*13 + mi;
    int mc = m > 207 ? 207 : m;      // slot (15,13) provably never read
    int d = threadIdx.x;
    float q0 = Q[mc*4+0], q1 = Q[mc*4+1], q2 = Q[mc*4+2], q3 = Q[mc*4+3];
    size_t base = (size_t)blk*WROW;
    int c = d >> 4, dl = d & 15;     // chunked [ak][d16] layout
#pragma unroll
    for (int ak = 0; ak < NA; ++ak) {
        int e = (ak*16 + hk)*4;
        float w = q0*Wk[(size_t)(e+0)*NDM + d] + q1*Wk[(size_t)(e+1)*NDM + d]
                + q2*Wk[(size_t)(e+2)*NDM + d] + q3*Wk[(size_t)(e+3)*NDM + d];
        weff3[base + (size_t)(c*13 + ak)*16 + dl] = w;
    }
    if (d < NA && m <= 207) {
        int e = (d*16 + hk)*4;
        beff2[(m*16 + hk)*NA + d] = q0*bk[e] + q1*bk[e+1] + q2*bk[e+2] + q3*bk[e+3];
    }
}

// ---------------- K1: conv 1x1 + GroupNorm -> vgT[b][d][64] (t-padded, coalesced)
#define VT_S 66
#define K1_LDS_BYTES ((NDM*VT_S + NT*NC)*4)

__launch_bounds__(1024, 8)
__global__ void ltae_convgn(const float* __restrict__ x, const float* __restrict__ Wc,
                            const float* __restrict__ bc, const float* __restrict__ gnw,
                            const float* __restrict__ gnb, float* __restrict__ vgT) {
    extern __shared__ float smem[];
    float* Vt = smem;
    float* xs = smem + NDM*VT_S;
    int b = blockIdx.x, tid = threadIdx.x;
    if (tid < NT*NC) xs[tid] = x[(size_t)b*NT*NC + tid];
    __syncthreads();
    {
        int d = tid >> 2, q = tid & 3;   // wave = 16 d = one GN group
        float wc[NC];
#pragma unroll
        for (int c = 0; c < NC; ++c) wc[c] = Wc[d*NC + c];
        float bcv = bc[d];
        float h[15];
        float s1 = 0.f, s2 = 0.f;
#pragma unroll
        for (int k = 0; k < 15; ++k) {
            int t = 15*q + k;
            float a = bcv;
#pragma unroll
            for (int c = 0; c < NC; ++c) a = fmaf(xs[t*NC + c], wc[c], a);
            h[k] = a; s1 += a; s2 += a*a;
        }
#pragma unroll
        for (int off = 1; off < 64; off <<= 1) {
            s1 += __shfl_xor(s1, off);
            s2 += __shfl_xor(s2, off);
        }
        float mean = s1 * (1.f/960.f);
        float var  = s2 * (1.f/960.f) - mean*mean;
        float rstd = rsqrtf(var + 1e-5f);
        float g = gnw[d], bb = gnb[d];
#pragma unroll
        for (int k = 0; k < 15; ++k)
            Vt[d*VT_S + 15*q + k] = (h[k]-mean)*rstd*g + bb;
    }
    __syncthreads();
    float* vb = vgT + (size_t)b*NDM*64;
    for (int i = tid; i < NDM*64; i += 1024) {
        int d = i >> 6, t = i & 63;
        vb[i] = (t < NT) ? Vt[d*VT_S + t] : 0.f;
    }
}

// ---------------- K2: scrambled attention; block = (b, hk-quadrant), wave = hk
// Weights: half-row (8 chunks, 6.6 KB) staged into wave-private LDS via
// cooperative load+ds_write (compiler-tracked deps), consumed by
// uniform-address ds_read_b128 broadcast (conflict-free, in-order lgkm).
// v: coalesced per-lane scalar global loads (vmcnt). No s_load, no VGPR dbuf.
#define WL_F 1664                       // 8 chunks x 208 floats per wave slot
#define FMA16(ACC, V, W0, W1, W2, W3) do { \
    ACC = fmaf(V[0],  W0.x, ACC); ACC = fmaf(V[1],  W0.y, ACC); \
    ACC = fmaf(V[2],  W0.z, ACC); ACC = fmaf(V[3],  W0.w, ACC); \
    ACC = fmaf(V[4],  W1.x, ACC); ACC = fmaf(V[5],  W1.y, ACC); \
    ACC = fmaf(V[6],  W1.z, ACC); ACC = fmaf(V[7],  W1.w, ACC); \
    ACC = fmaf(V[8],  W2.x, ACC); ACC = fmaf(V[9],  W2.y, ACC); \
    ACC = fmaf(V[10], W2.z, ACC); ACC = fmaf(V[11], W2.w, ACC); \
    ACC = fmaf(V[12], W3.x, ACC); ACC = fmaf(V[13], W3.y, ACC); \
    ACC = fmaf(V[14], W3.z, ACC); ACC = fmaf(V[15], W3.w, ACC); } while (0)

__launch_bounds__(256, 6)
__global__ void ltae_attn(const float* __restrict__ vgT, const float* __restrict__ weff3,
                          const float* __restrict__ beff2, float* __restrict__ attout) {
    __shared__ float wlds[4*WL_F];      // 26,624 B -> 6 blocks/CU
    int bq = blockIdx.x;
    int b = bq >> 2, q = bq & 3;
    int tid = threadIdx.x;
    int wid = tid >> 6, lane = tid & 63;
    int hk = q*4 + wid;
    int tk = lane;
    int mi    = (13*b) >> 10;                        // block-uniform
    int rstar = ((mi+1) << 10) - 13*b;               // switch iff <13
    int hb13  = (hk*1024 + b)*13;
    const float* __restrict__ vb = vgT + (size_t)b*NDM*64;
    float* wl = wlds + wid*WL_F;                     // wave-private slot
    bool ld = (lane < 52);

    float acc[13];
#pragma unroll
    for (int j = 0; j < 13; ++j) acc[j] = 0.f;

    // ---- pass A: row (hk, mi); 2 halves x 8 chunks
    {
        const float* __restrict__ wrow = weff3 + (size_t)(hk*14 + mi)*WROW;
#pragma unroll 1
        for (int h = 0; h < 2; ++h) {
            // stage half h: 8 chunks x 208 floats (lanes 0-51 x float4 each chunk)
            if (ld) {
#pragma unroll
                for (int s = 0; s < 8; ++s) {
                    float4 w = *(const float4*)(wrow + h*WL_F + s*208 + lane*4);
                    *(float4*)(wl + s*208 + lane*4) = w;
                }
            }
            LDS_FENCE();
#pragma unroll 1
            for (int c8 = 0; c8 < 8; ++c8) {
                int c = h*8 + c8;
                float v[16];
#pragma unroll
                for (int dd = 0; dd < 16; ++dd) v[dd] = vb[(c*16+dd)*64 + tk];
                const float* wc = wl + c8*208;
#pragma unroll
                for (int ak = 0; ak < 13; ++ak) {
                    const float* wp = wc + ak*16;
                    float4 w0 = *(const float4*)(wp);
                    float4 w1 = *(const float4*)(wp+4);
                    float4 w2 = *(const float4*)(wp+8);
                    float4 w3 = *(const float4*)(wp+12);
                    FMA16(acc[ak], v, w0, w1, w2, w3);
                }
            }
        }
    }

    // ---- pass B (rare, block-uniform): row (hk, mi+1); direct global reads.
    if (rstar < 13) {
        int ustar = 60*rstar;
        int tstar = ustar / 13;
        if (tk == tstar) {
#pragma unroll
            for (int j = 0; j < 13; ++j) wl[j] = acc[j];
        }
        LDS_FENCE();
        if (tk >= tstar) {
#pragma unroll
            for (int j = 0; j < 13; ++j) acc[j] = 0.f;
            const float4* __restrict__ wr4 = (const float4*)(weff3 + (size_t)(hk*14 + mi + 1)*WROW);
#pragma unroll 1
            for (int c = 0; c < 16; ++c) {
                float v[16];
#pragma unroll
                for (int dd = 0; dd < 16; ++dd) v[dd] = vb[(c*16+dd)*64 + tk];
#pragma unroll
                for (int ak = 0; ak < 13; ++ak) {
                    float4 w0 = wr4[(c*13+ak)*4+0];
                    float4 w1 = wr4[(c*13+ak)*4+1];
                    float4 w2 = wr4[(c*13+ak)*4+2];
                    float4 w3 = wr4[(c*13+ak)*4+3];
                    FMA16(acc[ak], v, w0, w1, w2, w3);
                }
            }
        }
        if (tk == tstar) {
#pragma unroll
            for (int j = 0; j < 13; ++j)
                if (13*tk + j < ustar) acc[j] = wl[j];
        }
    }

    // ---- phased softmax + AV (5 u-ranges; wave slot reused as 192-float buffer)
    float* myC = wl;
    int dh = lane >> 2, cc = lane & 3;
    float vreg[15];
#pragma unroll
    for (int j = 0; j < 15; ++j) vreg[j] = vb[(hk*16 + dh)*64 + cc + 4*j];

    const int ULO[5] = {0, 180, 360, 540, 720};
    const int RLO[5] = {0, 3, 6, 9, 12};
    const int RHI[5] = {3, 6, 9, 12, 13};
#pragma unroll 1
    for (int p = 0; p < 5; ++p) {
        int ulo = ULO[p];
        int uhi = (p == 4) ? 780 : ulo + 180;
        if (tk < NT) {
#pragma unroll
            for (int j = 0; j < 13; ++j) {
                int u = 13*tk + j;
                if (u >= ulo && u < uhi) myC[u - ulo] = acc[j];
            }
        }
        LDS_FENCE();
        for (int r = RLO[p]; r < RHI[p]; ++r) {
            int n = hb13 + r;
            int m = n >> 10;                         // exact variant for this row
            int brow = (m*16 + hk)*13;
            float logit = -1e30f;
            if (lane < NT) {
                int u  = r*60 + lane;
                int ak = u % 13;
                logit = (myC[u - ulo] + beff2[brow + ak]) * 0.5f;
            }
            float mx = logit;
#pragma unroll
            for (int off = 32; off; off >>= 1) mx = fmaxf(mx, __shfl_xor(mx, off));
            float e = (lane < NT) ? __expf(logit - mx) : 0.f;
            float s = e;
#pragma unroll
            for (int off = 32; off; off >>= 1) s += __shfl_xor(s, off);
            float attn = e / s;
            if (lane < NT) myC[r*60 - ulo + lane] = attn;  // same-wave in-order LDS
            LDS_FENCE();
            float a = 0.f;
#pragma unroll
            for (int j = 0; j < 15; ++j)
                a = fmaf(myC[r*60 - ulo + cc + 4*j], vreg[j], a);
            a += __shfl_xor(a, 1);
            a += __shfl_xor(a, 2);
            if (cc == 0) attout[(size_t)n*NDH + dh] = a;
        }
    }
}

// ---------------- K3: MLP + BN(eval) + ReLU + GroupNorm(16,128); 16 rows/block,
// each thread computes 2 rows per W1-row load.
__launch_bounds__(1024)
__global__ void ltae_mlp(const float* __restrict__ attout, const float* __restrict__ W1,
                         const float* __restrict__ b1, const float* __restrict__ bnw,
                         const float* __restrict__ bnb, const float* __restrict__ bnrm,
                         const float* __restrict__ bnrv, const float* __restrict__ gow,
                         const float* __restrict__ gob, float* __restrict__ out) {
    __shared__ float f[16][NDM];
    int tid = threadIdx.x;
    int sl  = tid >> 7;          // 0..7
    int j   = tid & 127;
    int base = blockIdx.x << 4;  // 16 sids per block; sid = a2*1024 + b2
    for (int k = tid; k < 16*NDM; k += 1024) {
        int s = k >> 8, c = k & 255;
        int sid2 = base + s;
        int aa = sid2 >> 10, bb = sid2 & 1023;
        int h2 = c >> 4, dhh = c & 15;
        f[s][c] = attout[((size_t)((aa*16 + h2)*1024 + bb))*NDH + dhh];
    }
    __syncthreads();
    const float* fr0 = f[sl];
    const float* fr1 = f[sl + 8];
    const float* w   = &W1[(size_t)j*NDM];
    float bj = b1[j];
    float acc0 = bj, acc1 = bj;
    for (int c = 0; c < NDM; c += 4) {
        float4 wv = *(const float4*)&w[c];
        acc0 += wv.x*fr0[c] + wv.y*fr0[c+1] + wv.z*fr0[c+2] + wv.w*fr0[c+3];
        acc1 += wv.x*fr1[c] + wv.y*fr1[c+1] + wv.z*fr1[c+2] + wv.w*fr1[c+3];
    }
    float rs = rsqrtf(bnrv[j] + 1e-5f);
    float sc = rs * bnw[j];
    float sh = bnb[j] - bnrm[j]*sc;
    float y0 = fmaxf(acc0*sc + sh, 0.f);
    float y1 = fmaxf(acc1*sc + sh, 0.f);
    float a1 = y0, b1s = y0*y0, a2 = y1, b2s = y1*y1;
#pragma unroll
    for (int off = 1; off < 8; off <<= 1) {
        a1  += __shfl_xor(a1, off);
        b1s += __shfl_xor(b1s, off);
        a2  += __shfl_xor(a2, off);
        b2s += __shfl_xor(b2s, off);
    }
    float gw = gow[j], gb = gob[j];
    {
        float mean = a1 * 0.125f;
        float var  = b1s * 0.125f - mean*mean;
        float o = (y0 - mean) * rsqrtf(var + 1e-5f) * gw + gb;
        int sid = base + sl, aa = sid >> 10, bb = sid & 1023;
        out[((size_t)bb*NA + aa)*NMO + j] = o;
    }
    {
        float mean = a2 * 0.125f;
        float var  = b2s * 0.125f - mean*mean;
        float o = (y1 - mean) * rsqrtf(var + 1e-5f) * gw + gb;
        int sid = base + sl + 8, aa = sid >> 10, bb = sid & 1023;
        out[((size_t)bb*NA + aa)*NMO + j] = o;
    }
}

extern "C" void kernel_launch(void* const* d_in, const int* in_sizes, int n_in,
                              void* d_out, int out_size, void* d_ws, size_t ws_size,
                              hipStream_t stream) {
    const float* x    = (const float*)d_in[0];
    const float* Wc   = (const float*)d_in[1];
    const float* bc   = (const float*)d_in[2];
    const float* gnw  = (const float*)d_in[3];
    const float* gnb  = (const float*)d_in[4];
    const float* Q    = (const float*)d_in[5];
    const float* Wk   = (const float*)d_in[6];
    const float* bk   = (const float*)d_in[7];
    const float* W1   = (const float*)d_in[8];
    const float* b1   = (const float*)d_in[9];
    const float* bnw  = (const float*)d_in[10];
    const float* bnb  = (const float*)d_in[11];
    const float* bnrm = (const float*)d_in[12];
    const float* bnrv = (const float*)d_in[13];
    const float* gow  = (const float*)d_in[14];
    const float* gob  = (const float*)d_in[15];

    float* ws     = (float*)d_ws;
    float* weff3  = ws + OFF_WEFF;
    float* beff2  = ws + OFF_BEFF;
    float* vgT    = ws + OFF_VGT;
    float* attout = ws + OFF_ATT;
    float* outp   = (float*)d_out;

    hipLaunchKernelGGL(ltae_weff, dim3(NH*14), dim3(256), 0, stream, Q, Wk, bk, weff3, beff2);
    hipFuncSetAttribute((const void*)ltae_convgn,
                        hipFuncAttributeMaxDynamicSharedMemorySize, K1_LDS_BYTES);
    hipLaunchKernelGGL(ltae_convgn, dim3(NB), dim3(1024), K1_LDS_BYTES, stream,
                       x, Wc, bc, gnw, gnb, vgT);
    hipLaunchKernelGGL(ltae_attn, dim3(NB*4), dim3(256), 0, stream,
                       vgT, weff3, beff2, attout);
    hipLaunchKernelGGL(ltae_mlp, dim3(NA*NB/16), dim3(1024), 0, stream,
                       attout, W1, b1, bnw, bnb, bnrm, bnrv, gow, gob, outp);
}